// Round 9
// baseline (101.246 us; speedup 1.0000x reference)
//
#include <hip/hip_runtime.h>

// DIAGNOSTIC ROUND: identical to R8 except cd_mfma runs its 128-tile MFMA
// loop PASSES=6 times (idempotent fmin; barrier+asm fence between passes).
// dur - 32.2 = 5 * T_tileloop; 6x should surface cd_mfma in top-5 counters.

typedef __bf16 bf16x8  __attribute__((ext_vector_type(8)));
typedef float  f32x16  __attribute__((ext_vector_type(16)));

#define BATCH 8
#define NPTS 4096
#define NCLOUD (BATCH*NPTS)
#define DIRB 16
#define COLTILES (NPTS/32)
#define K1_BLOCKS (DIRB*COLTILES/4)  // 512
#define NWAVES (DIRB*COLTILES)       // 2048
#define PASSES 6                     // DIAGNOSTIC multiplier

__device__ __forceinline__ unsigned short f2bf(float f) {   // RTNE
    unsigned u = __float_as_uint(f);
    unsigned r = u + 0x7FFFu + ((u >> 16) & 1u);
    return (unsigned short)(r >> 16);
}
__device__ __forceinline__ float bf2f(unsigned short h) {
    return __uint_as_float(((unsigned)h) << 16);
}

__global__ __launch_bounds__(256) void cd_prep(
        const float* __restrict__ pred,
        const float* __restrict__ targ,
        uint4* __restrict__ dbpack,
        uint4* __restrict__ qpack,
        float* __restrict__ nqtab) {
    int i = blockIdx.x * 256 + threadIdx.x;
    const float* src = (i < NCLOUD) ? pred : targ;
    const float* p = src + (size_t)(i & (NCLOUD - 1)) * 3;
    unsigned short bx = f2bf(p[0]), by = f2bf(p[1]), bz = f2bf(p[2]);
    float xr = bf2f(bx), yr = bf2f(by), zr = bf2f(bz);
    float w = fmaf(xr, xr, fmaf(yr, yr, zr * zr));
    unsigned short hi = f2bf(w);
    unsigned short lo = f2bf(w - bf2f(hi));
    unsigned short mx = f2bf(-2.f * xr), my = f2bf(-2.f * yr), mz = f2bf(-2.f * zr);
    const unsigned short one = 0x3F80;

    dbpack[i] = make_uint4((unsigned)bx | ((unsigned)by << 16),
                           (unsigned)bz | ((unsigned)hi << 16),
                           (unsigned)lo, 0u);
    qpack[i]  = make_uint4((unsigned)mx | ((unsigned)my << 16),
                           (unsigned)mz | ((unsigned)one << 16),
                           (unsigned)one, 0u);
    nqtab[i]  = w;
}

__global__ __launch_bounds__(256, 2) void cd_mfma(
        const uint4* __restrict__ dbpack,
        const uint4* __restrict__ qpack,
        const float* __restrict__ nqtab,
        float* __restrict__ Bsum) {
    __shared__ uint4 sdb[NPTS + 1];
    const int bx   = blockIdx.x;
    const int tid  = threadIdx.x;
    const int dirb = bx >> 5;
    const int ctg  = bx & 31;
    const int wave = tid >> 6;
    const int lane = tid & 63;
    const int dir  = dirb >> 3;
    const int b    = dirb & 7;
    const int dbc  = 1 - dir;
    const int qc   = dir;

    const uint4* src = dbpack + ((size_t)dbc * NCLOUD + (size_t)b * NPTS);
    for (int i = tid; i < NPTS; i += 256) sdb[i] = src[i];
    if (tid == 0) sdb[NPTS] = make_uint4(0u, 0u, 0u, 0u);
    __syncthreads();

    const int coltile = ctg * 4 + wave;
    const int q = coltile * 32 + (lane & 31);
    uint4 qv = qpack[(size_t)qc * NCLOUD + (size_t)b * NPTS + q];
    uint4 z4 = make_uint4(0u, 0u, 0u, 0u);
    uint4 bqv = (lane < 32) ? qv : z4;
    bf16x8 Bf = __builtin_bit_cast(bf16x8, bqv);

    const char* sb = (const char*)sdb;
    const int off0 = (lane < 32) ? ((lane & 31) * 16) : (NPTS * 16);
    const int step = (lane < 32) ? 512 : 0;

    const float inf = __uint_as_float(0x7F800000u);
    float m0 = inf, m1 = inf;
    auto fold = [&](const f32x16& a) {
        m0 = fminf(m0, fminf(a[0],  a[1]));
        m0 = fminf(m0, fminf(a[2],  a[3]));
        m0 = fminf(m0, fminf(a[4],  a[5]));
        m0 = fminf(m0, fminf(a[6],  a[7]));
        m1 = fminf(m1, fminf(a[8],  a[9]));
        m1 = fminf(m1, fminf(a[10], a[11]));
        m1 = fminf(m1, fminf(a[12], a[13]));
        m1 = fminf(m1, fminf(a[14], a[15]));
    };

    for (int pass = 0; pass < PASSES; ++pass) {   // DIAGNOSTIC: 6x tile loop
        int off = off0;
        uint4 a0 = *(const uint4*)(sb + off); off += step;
        f32x16 accA = __builtin_amdgcn_mfma_f32_32x32x16_bf16(
                __builtin_bit_cast(bf16x8, a0), Bf, (f32x16){}, 0, 0, 0);
        uint4 a1 = *(const uint4*)(sb + off); off += step;
        f32x16 accB = __builtin_amdgcn_mfma_f32_32x32x16_bf16(
                __builtin_bit_cast(bf16x8, a1), Bf, (f32x16){}, 0, 0, 0);
        #pragma unroll 4
        for (int j = 2; j < COLTILES; j += 2) {
            uint4 an = *(const uint4*)(sb + off); off += step;
            fold(accA);
            accA = __builtin_amdgcn_mfma_f32_32x32x16_bf16(
                    __builtin_bit_cast(bf16x8, an), Bf, (f32x16){}, 0, 0, 0);
            uint4 am = *(const uint4*)(sb + off); off += step;
            fold(accB);
            accB = __builtin_amdgcn_mfma_f32_32x32x16_bf16(
                    __builtin_bit_cast(bf16x8, am), Bf, (f32x16){}, 0, 0, 0);
        }
        fold(accA);
        fold(accB);
        __syncthreads();                 // block cross-pass CSE/motion
        asm volatile("" ::: "memory");
    }

    float m = fminf(m0, m1);
    m = fminf(m, __shfl_xor(m, 32, 64));
    float nq = nqtab[(size_t)qc * NCLOUD + (size_t)b * NPTS + q];
    float d = sqrtf(fmaxf(m + nq, 0.f));
    d += __shfl_xor(d, 16, 64);
    d += __shfl_xor(d,  8, 64);
    d += __shfl_xor(d,  4, 64);
    d += __shfl_xor(d,  2, 64);
    d += __shfl_xor(d,  1, 64);
    if (lane == 0) Bsum[bx * 4 + wave] = d;
}

__global__ __launch_bounds__(256) void cd_final(
        const float* __restrict__ Bsum, float* __restrict__ out) {
    const int tid = threadIdx.x;
    float s = 0.f;
    #pragma unroll
    for (int i = 0; i < NWAVES; i += 256) s += Bsum[tid + i];
    __shared__ float red[256];
    red[tid] = s;
    __syncthreads();
    for (int off = 128; off > 0; off >>= 1) {
        if (tid < off) red[tid] += red[tid + off];
        __syncthreads();
    }
    if (tid == 0) out[0] = red[0] * (1.0f / (float)(BATCH * NPTS));
}

extern "C" void kernel_launch(void* const* d_in, const int* in_sizes, int n_in,
                              void* d_out, int out_size, void* d_ws, size_t ws_size,
                              hipStream_t stream) {
    const float* pred = (const float*)d_in[0];
    const float* targ = (const float*)d_in[1];
    char* ws = (char*)d_ws;
    uint4* dbpack = (uint4*)(ws);
    uint4* qpack  = (uint4*)(ws + (size_t)2 * NCLOUD * 16);
    float* nqtab  = (float*)(ws + (size_t)4 * NCLOUD * 16);
    float* Bsum   = (float*)(ws + (size_t)4 * NCLOUD * 16 + (size_t)2 * NCLOUD * 4);
    float* out    = (float*)d_out;

    cd_prep<<<2 * NCLOUD / 256, 256, 0, stream>>>(pred, targ, dbpack, qpack, nqtab);
    cd_mfma<<<K1_BLOCKS, 256, 0, stream>>>(dbpack, qpack, nqtab, Bsum);
    cd_final<<<1, 256, 0, stream>>>(Bsum, out);
}

// Round 10
// 25.489 us; speedup vs baseline: 3.9721x; 3.9721x over previous
//
#include <hip/hip_runtime.h>

// Chamfer distance, B=8, N=M=4096, fp32 in/out — fused MFMA (bf16) path.
//   d^2 = |q~|^2 + (hi+lo) - 2 q~.b~   via  mfma_f32_32x32x16_bf16
//   A (32x16) = db tile rows, k = {x~, y~, z~, hi(|b~|^2), lo, 0...}
//   B (16x32) = query cols,   k = {-2x~, -2y~, -2z~, 1, 1, 0...} (k>=8 lanes = 0)
//   C layout: col = lane&31 (query), rows = db -> min over db is IN-LANE.
// K1 cd_mfma:  per (dirb, 4-coltile) block: pack db inline -> 64KB LDS, each
//              wave: 128 MFMA tiles + in-lane min3-fold, sqrt+sum epilogue,
//              one float per wave -> Bsum[2048]. Zero atomics, no prep pass.
// K2 cd_final: 1 block sums Bsum deterministically -> loss.

typedef __bf16 bf16x8  __attribute__((ext_vector_type(8)));
typedef float  f32x16  __attribute__((ext_vector_type(16)));

#define BATCH 8
#define NPTS 4096
#define NCLOUD (BATCH*NPTS)
#define DBTILES (NPTS/32)            // 128 db tiles per dirb
#define K1_BLOCKS 512                // 16 dirb x 32 coltile-groups
#define NWAVES 2048

__device__ __forceinline__ unsigned short f2bf(float f) {   // RTNE
    unsigned u = __float_as_uint(f);
    unsigned r = u + 0x7FFFu + ((u >> 16) & 1u);
    return (unsigned short)(r >> 16);
}
__device__ __forceinline__ float bf2f(unsigned short h) {
    return __uint_as_float(((unsigned)h) << 16);
}

__global__ __launch_bounds__(256, 2) void cd_mfma(
        const float* __restrict__ pred,
        const float* __restrict__ targ,
        float* __restrict__ Bsum) {
    __shared__ uint4 sdb[NPTS];          // 64 KB packed db
    const int bx   = blockIdx.x;         // 0..511
    const int tid  = threadIdx.x;
    const int dirb = bx >> 5;            // 0..15
    const int ctg  = bx & 31;
    const int wave = tid >> 6;
    const int lane = tid & 63;
    const int dir  = dirb >> 3;
    const int b    = dirb & 7;
    const float* Qraw = (dir ? targ : pred) + (size_t)b * NPTS * 3;
    const float* Draw = (dir ? pred : targ) + (size_t)b * NPTS * 3;

    // stage + bf16-pack db cloud for this dirb
    for (int i = tid; i < NPTS; i += 256) {
        const float* p = Draw + (size_t)i * 3;
        unsigned short px = f2bf(p[0]), py = f2bf(p[1]), pz = f2bf(p[2]);
        float xr = bf2f(px), yr = bf2f(py), zr = bf2f(pz);
        float w  = fmaf(xr, xr, fmaf(yr, yr, zr * zr));
        unsigned short hi = f2bf(w);
        unsigned short lo = f2bf(w - bf2f(hi));
        sdb[i] = make_uint4((unsigned)px | ((unsigned)py << 16),
                            (unsigned)pz | ((unsigned)hi << 16),
                            (unsigned)lo, 0u);
    }

    // query packet (overlaps staging loads)
    const int q = (ctg * 4 + wave) * 32 + (lane & 31);
    const float* qp = Qraw + (size_t)q * 3;
    unsigned short ax = f2bf(qp[0]), ay = f2bf(qp[1]), az = f2bf(qp[2]);
    float xr = bf2f(ax), yr = bf2f(ay), zr = bf2f(az);
    float nq = fmaf(xr, xr, fmaf(yr, yr, zr * zr));
    unsigned short mx = f2bf(-2.f * xr), my = f2bf(-2.f * yr), mz = f2bf(-2.f * zr);
    const unsigned one = 0x3F80u;
    uint4 qv = make_uint4((unsigned)mx | ((unsigned)my << 16),
                          (unsigned)mz | (one << 16), one, 0u);
    uint4 bqv = (lane < 32) ? qv : make_uint4(0u, 0u, 0u, 0u);
    bf16x8 Bf = __builtin_bit_cast(bf16x8, bqv);

    __syncthreads();

    // A addressing: all lanes read row (lane&31); k>=8 lanes' values are
    // multiplied by B's zeros, so duplicates are harmless (finite bf16).
    const char* sb = (const char*)sdb;
    int off = (lane & 31) * 16;

    const f32x16 Z = {};                 // hoisted zero C operand
    const float inf = __uint_as_float(0x7F800000u);
    float m0 = inf, m1 = inf;
    auto fold = [&](const f32x16& a) {
        m0 = fminf(m0, fminf(a[0],  a[1]));
        m0 = fminf(m0, fminf(a[2],  a[3]));
        m0 = fminf(m0, fminf(a[4],  a[5]));
        m0 = fminf(m0, fminf(a[6],  a[7]));
        m1 = fminf(m1, fminf(a[8],  a[9]));
        m1 = fminf(m1, fminf(a[10], a[11]));
        m1 = fminf(m1, fminf(a[12], a[13]));
        m1 = fminf(m1, fminf(a[14], a[15]));
    };

    uint4 a0 = *(const uint4*)(sb + off); off += 512;
    f32x16 accA = __builtin_amdgcn_mfma_f32_32x32x16_bf16(
            __builtin_bit_cast(bf16x8, a0), Bf, Z, 0, 0, 0);
    uint4 a1 = *(const uint4*)(sb + off); off += 512;
    f32x16 accB = __builtin_amdgcn_mfma_f32_32x32x16_bf16(
            __builtin_bit_cast(bf16x8, a1), Bf, Z, 0, 0, 0);
    #pragma unroll 8
    for (int j = 2; j < DBTILES; j += 2) {
        uint4 an = *(const uint4*)(sb + off); off += 512;
        fold(accA);
        accA = __builtin_amdgcn_mfma_f32_32x32x16_bf16(
                __builtin_bit_cast(bf16x8, an), Bf, Z, 0, 0, 0);
        uint4 am = *(const uint4*)(sb + off); off += 512;
        fold(accB);
        accB = __builtin_amdgcn_mfma_f32_32x32x16_bf16(
                __builtin_bit_cast(bf16x8, am), Bf, Z, 0, 0, 0);
    }
    fold(accA);
    fold(accB);

    // epilogue: combine row-halves, add |q~|^2, sqrt, sum 32 queries
    float m = fminf(m0, m1);
    m = fminf(m, __shfl_xor(m, 32, 64));
    float d = sqrtf(fmaxf(m + nq, 0.f));
    d += __shfl_xor(d, 16, 64);
    d += __shfl_xor(d,  8, 64);
    d += __shfl_xor(d,  4, 64);
    d += __shfl_xor(d,  2, 64);
    d += __shfl_xor(d,  1, 64);
    if (lane == 0) Bsum[bx * 4 + wave] = d;
}

__global__ __launch_bounds__(256) void cd_final(
        const float* __restrict__ Bsum, float* __restrict__ out) {
    const int tid = threadIdx.x;
    float s = 0.f;
    #pragma unroll
    for (int i = 0; i < NWAVES; i += 256) s += Bsum[tid + i];
    __shared__ float red[256];
    red[tid] = s;
    __syncthreads();
    for (int off = 128; off > 0; off >>= 1) {
        if (tid < off) red[tid] += red[tid + off];
        __syncthreads();
    }
    if (tid == 0) out[0] = red[0] * (1.0f / (float)(BATCH * NPTS));
}

extern "C" void kernel_launch(void* const* d_in, const int* in_sizes, int n_in,
                              void* d_out, int out_size, void* d_ws, size_t ws_size,
                              hipStream_t stream) {
    const float* pred = (const float*)d_in[0];
    const float* targ = (const float*)d_in[1];
    float* Bsum = (float*)d_ws;     // 8 KB
    float* out  = (float*)d_out;

    cd_mfma<<<K1_BLOCKS, 256, 0, stream>>>(pred, targ, Bsum);
    cd_final<<<1, 256, 0, stream>>>(Bsum, out);
}

// Round 11
// 16.247 us; speedup vs baseline: 6.2316x; 1.5688x over previous
//
#include <hip/hip_runtime.h>

// Chamfer distance, B=8, N=M=4096, fp32 in/out — fused MFMA (f16, K=8) path.
//   d^2 = |q~|^2 + (hi+lo) - 2 q~.b~   via  v_mfma_f32_32x32x8_f16
//   A (32x8) = db tile: lanes 0-31 row=lane k=0..3 {x,y,z,hi};
//                       lanes 32-63 row=lane-32 k=4..7 {lo,0,0,0}
//   B (8x32) = queries: lanes 0-31 col=lane k=0..3 {-2x,-2y,-2z,1};
//                       lanes 32-63 col=lane-32 k=4..7 {1,0,0,0}
//   C: col = lane&31 (query); 16 regs x 2 lane-halves cover all 32 db rows
//      (any bijection works — we min over rows and shfl-merge halves).
// K1 cd_mfma:  per (dirb, 4-coltile) block: pack db inline -> 64KB LDS; wave:
//              128 MFMA tiles (4-deep), v_min3 tree-fold, sqrt+sum epilogue,
//              one float per wave -> Bsum[2048]. Zero atomics.
// K2 cd_final: 1 block sums Bsum deterministically -> loss.

typedef _Float16 f16x4 __attribute__((ext_vector_type(4)));
typedef _Float16 f16x8 __attribute__((ext_vector_type(8)));
typedef float    f32x16 __attribute__((ext_vector_type(16)));

#define BATCH 8
#define NPTS 4096
#define DBTILES (NPTS/32)            // 128
#define K1_BLOCKS 512                // 16 dirb x 32 coltile-groups
#define NWAVES 2048

__device__ __forceinline__ float min3f(float a, float b, float c) {
    return fminf(fminf(a, b), c);    // -> v_min3_f32
}

__global__ __launch_bounds__(256, 2) void cd_mfma(
        const float* __restrict__ pred,
        const float* __restrict__ targ,
        float* __restrict__ Bsum) {
    __shared__ uint4 sdb[NPTS];          // 64 KB packed db
    const int bx   = blockIdx.x;
    const int tid  = threadIdx.x;
    const int dirb = bx >> 5;
    const int ctg  = bx & 31;
    const int wave = tid >> 6;
    const int lane = tid & 63;
    const int dir  = dirb >> 3;
    const int b    = dirb & 7;
    const float* Qraw = (dir ? targ : pred) + (size_t)b * NPTS * 3;
    const float* Draw = (dir ? pred : targ) + (size_t)b * NPTS * 3;

    // stage + f16-pack db cloud: packet = {x,y,z,hi | lo,0,0,0}
    for (int i = tid; i < NPTS; i += 256) {
        const float* p = Draw + (size_t)i * 3;
        _Float16 hx = (_Float16)p[0], hy = (_Float16)p[1], hz = (_Float16)p[2];
        float xr = (float)hx, yr = (float)hy, zr = (float)hz;
        float w  = fmaf(xr, xr, fmaf(yr, yr, zr * zr));
        _Float16 hhi = (_Float16)w;
        _Float16 hlo = (_Float16)(w - (float)hhi);
        f16x8 pkt = {hx, hy, hz, hhi, hlo, (_Float16)0.f, (_Float16)0.f, (_Float16)0.f};
        sdb[i] = __builtin_bit_cast(uint4, pkt);
    }

    // query packet (overlaps staging loads)
    const int q = (ctg * 4 + wave) * 32 + (lane & 31);
    const float* qp = Qraw + (size_t)q * 3;
    _Float16 qhx = (_Float16)qp[0], qhy = (_Float16)qp[1], qhz = (_Float16)qp[2];
    float xr = (float)qhx, yr = (float)qhy, zr = (float)qhz;
    float nq = fmaf(xr, xr, fmaf(yr, yr, zr * zr));
    _Float16 mx = (_Float16)(-2.f * xr), my = (_Float16)(-2.f * yr),
             mz = (_Float16)(-2.f * zr), one = (_Float16)1.f, zz = (_Float16)0.f;
    f16x4 Bf = (lane < 32) ? (f16x4){mx, my, mz, one}
                           : (f16x4){one, zz, zz, zz};

    __syncthreads();

    // A addressing: lanes 0-31 read packet bytes 0-7; lanes 32-63 bytes 8-15
    const char* sb = (const char*)sdb;
    int off = (lane & 31) * 16 + ((lane >> 5) << 3);

    const f32x16 Z = {};
    const float inf = __uint_as_float(0x7F800000u);
    float m = inf;
    auto fold = [&](const f32x16& a) {
        float s0 = min3f(a[0],  a[1],  a[2]);
        float s1 = min3f(a[3],  a[4],  a[5]);
        float s2 = min3f(a[6],  a[7],  a[8]);
        float s3 = min3f(a[9],  a[10], a[11]);
        float s4 = min3f(a[12], a[13], a[14]);
        float t0 = min3f(s0, s1, s2);
        float t1 = min3f(s3, s4, a[15]);
        m = min3f(m, t0, t1);
    };
    auto rd = [&]() { f16x4 v = *(const f16x4*)(sb + off); off += 512; return v; };

    // 4-deep MFMA pipeline over 128 tiles
    f32x16 acc0 = __builtin_amdgcn_mfma_f32_32x32x8f16(rd(), Bf, Z, 0, 0, 0);
    f32x16 acc1 = __builtin_amdgcn_mfma_f32_32x32x8f16(rd(), Bf, Z, 0, 0, 0);
    f32x16 acc2 = __builtin_amdgcn_mfma_f32_32x32x8f16(rd(), Bf, Z, 0, 0, 0);
    f32x16 acc3 = __builtin_amdgcn_mfma_f32_32x32x8f16(rd(), Bf, Z, 0, 0, 0);
    #pragma unroll 4
    for (int j = 4; j < DBTILES; j += 4) {
        fold(acc0); acc0 = __builtin_amdgcn_mfma_f32_32x32x8f16(rd(), Bf, Z, 0, 0, 0);
        fold(acc1); acc1 = __builtin_amdgcn_mfma_f32_32x32x8f16(rd(), Bf, Z, 0, 0, 0);
        fold(acc2); acc2 = __builtin_amdgcn_mfma_f32_32x32x8f16(rd(), Bf, Z, 0, 0, 0);
        fold(acc3); acc3 = __builtin_amdgcn_mfma_f32_32x32x8f16(rd(), Bf, Z, 0, 0, 0);
    }
    fold(acc0); fold(acc1); fold(acc2); fold(acc3);

    // epilogue: merge lane-halves, add |q~|^2, sqrt, sum 32 queries
    m = fminf(m, __shfl_xor(m, 32, 64));
    float d = sqrtf(fmaxf(m + nq, 0.f));
    d += __shfl_xor(d, 16, 64);
    d += __shfl_xor(d,  8, 64);
    d += __shfl_xor(d,  4, 64);
    d += __shfl_xor(d,  2, 64);
    d += __shfl_xor(d,  1, 64);
    if (lane == 0) Bsum[bx * 4 + wave] = d;
}

__global__ __launch_bounds__(256) void cd_final(
        const float* __restrict__ Bsum, float* __restrict__ out) {
    const int tid = threadIdx.x;
    float s = 0.f;
    #pragma unroll
    for (int i = 0; i < NWAVES; i += 256) s += Bsum[tid + i];
    __shared__ float red[256];
    red[tid] = s;
    __syncthreads();
    for (int off = 128; off > 0; off >>= 1) {
        if (tid < off) red[tid] += red[tid + off];
        __syncthreads();
    }
    if (tid == 0) out[0] = red[0] * (1.0f / (float)(BATCH * NPTS));
}

extern "C" void kernel_launch(void* const* d_in, const int* in_sizes, int n_in,
                              void* d_out, int out_size, void* d_ws, size_t ws_size,
                              hipStream_t stream) {
    const float* pred = (const float*)d_in[0];
    const float* targ = (const float*)d_in[1];
    float* Bsum = (float*)d_ws;     // 8 KB
    float* out  = (float*)d_out;

    cd_mfma<<<K1_BLOCKS, 256, 0, stream>>>(pred, targ, Bsum);
    cd_final<<<1, 256, 0, stream>>>(Bsum, out);
}

// Round 12
// 15.292 us; speedup vs baseline: 6.6208x; 1.0625x over previous
//
#include <hip/hip_runtime.h>

// Chamfer distance, B=8, N=M=4096, fp32 in/out — fused MFMA (f16, K=8) path.
//   d^2 = |q~|^2 + (hi+lo) - 2 q~.b~   via  v_mfma_f32_32x32x8_f16
//   A (32x8) = db tile: lanes 0-31 row=lane k=0..3 {x,y,z,hi};
//                       lanes 32-63 row=lane-32 k=4..7 {lo,0,0,0}
//   B (8x32) = queries: lanes 0-31 col=lane k=0..3 {-2x,-2y,-2z,1};
//                       lanes 32-63 col=lane-32 k=4..7 {1,0,0,0}
//   C: col = lane&31 (query); 16 regs x 2 lane-halves cover all 32 db rows.
// K1 cd_mfma:  256 blocks x 512 thr (8 waves). Per (dirb, 8-coltile) block:
//              pack db inline -> 64KB LDS (8 iters/thread); per wave 128 MFMA
//              tiles (4-deep) + v_min3 tree-fold; sqrt+sum; block reduce ->
//              one float -> Bsum[256]. Zero atomics.
// K2 cd_final: 1 block (256 thr) sums Bsum deterministically -> loss.

typedef _Float16 f16x4 __attribute__((ext_vector_type(4)));
typedef _Float16 f16x8 __attribute__((ext_vector_type(8)));
typedef float    f32x16 __attribute__((ext_vector_type(16)));

#define BATCH 8
#define NPTS 4096
#define THREADS 512
#define WAVES 8
#define DBTILES (NPTS/32)            // 128
#define K1_BLOCKS 256                // 16 dirb x 16 coltile-groups

__device__ __forceinline__ float min3f(float a, float b, float c) {
    return fminf(fminf(a, b), c);    // -> v_min3_f32
}

__global__ __launch_bounds__(THREADS, 2) void cd_mfma(
        const float* __restrict__ pred,
        const float* __restrict__ targ,
        float* __restrict__ Bsum) {
    __shared__ uint4 sdb[NPTS];          // 64 KB packed db
    __shared__ float wred[WAVES];
    const int bx   = blockIdx.x;         // 0..255
    const int tid  = threadIdx.x;
    const int dirb = bx >> 4;            // 0..15
    const int ctg  = bx & 15;            // 0..15
    const int wave = tid >> 6;           // 0..7
    const int lane = tid & 63;
    const int dir  = dirb >> 3;
    const int b    = dirb & 7;
    const float* Qraw = (dir ? targ : pred) + (size_t)b * NPTS * 3;
    const float* Draw = (dir ? pred : targ) + (size_t)b * NPTS * 3;

    // stage + f16-pack db cloud: packet = {x,y,z,hi | lo,0,0,0}
    for (int i = tid; i < NPTS; i += THREADS) {
        const float* p = Draw + (size_t)i * 3;
        _Float16 hx = (_Float16)p[0], hy = (_Float16)p[1], hz = (_Float16)p[2];
        float xr = (float)hx, yr = (float)hy, zr = (float)hz;
        float w  = fmaf(xr, xr, fmaf(yr, yr, zr * zr));
        _Float16 hhi = (_Float16)w;
        _Float16 hlo = (_Float16)(w - (float)hhi);
        f16x8 pkt = {hx, hy, hz, hhi, hlo, (_Float16)0.f, (_Float16)0.f, (_Float16)0.f};
        sdb[i] = __builtin_bit_cast(uint4, pkt);
    }

    // query packet (overlaps staging loads)
    const int q = (ctg * WAVES + wave) * 32 + (lane & 31);
    const float* qp = Qraw + (size_t)q * 3;
    _Float16 qhx = (_Float16)qp[0], qhy = (_Float16)qp[1], qhz = (_Float16)qp[2];
    float xr = (float)qhx, yr = (float)qhy, zr = (float)qhz;
    float nq = fmaf(xr, xr, fmaf(yr, yr, zr * zr));
    _Float16 mx = (_Float16)(-2.f * xr), my = (_Float16)(-2.f * yr),
             mz = (_Float16)(-2.f * zr), one = (_Float16)1.f, zz = (_Float16)0.f;
    f16x4 Bf = (lane < 32) ? (f16x4){mx, my, mz, one}
                           : (f16x4){one, zz, zz, zz};

    __syncthreads();

    // A addressing: lanes 0-31 read packet bytes 0-7; lanes 32-63 bytes 8-15
    const char* sb = (const char*)sdb;
    int off = (lane & 31) * 16 + ((lane >> 5) << 3);

    const f32x16 Z = {};
    const float inf = __uint_as_float(0x7F800000u);
    float m = inf;
    auto fold = [&](const f32x16& a) {
        float s0 = min3f(a[0],  a[1],  a[2]);
        float s1 = min3f(a[3],  a[4],  a[5]);
        float s2 = min3f(a[6],  a[7],  a[8]);
        float s3 = min3f(a[9],  a[10], a[11]);
        float s4 = min3f(a[12], a[13], a[14]);
        float t0 = min3f(s0, s1, s2);
        float t1 = min3f(s3, s4, a[15]);
        m = min3f(m, t0, t1);
    };
    auto rd = [&]() { f16x4 v = *(const f16x4*)(sb + off); off += 512; return v; };

    // 4-deep MFMA pipeline over 128 tiles
    f32x16 acc0 = __builtin_amdgcn_mfma_f32_32x32x8f16(rd(), Bf, Z, 0, 0, 0);
    f32x16 acc1 = __builtin_amdgcn_mfma_f32_32x32x8f16(rd(), Bf, Z, 0, 0, 0);
    f32x16 acc2 = __builtin_amdgcn_mfma_f32_32x32x8f16(rd(), Bf, Z, 0, 0, 0);
    f32x16 acc3 = __builtin_amdgcn_mfma_f32_32x32x8f16(rd(), Bf, Z, 0, 0, 0);
    #pragma unroll 4
    for (int j = 4; j < DBTILES; j += 4) {
        fold(acc0); acc0 = __builtin_amdgcn_mfma_f32_32x32x8f16(rd(), Bf, Z, 0, 0, 0);
        fold(acc1); acc1 = __builtin_amdgcn_mfma_f32_32x32x8f16(rd(), Bf, Z, 0, 0, 0);
        fold(acc2); acc2 = __builtin_amdgcn_mfma_f32_32x32x8f16(rd(), Bf, Z, 0, 0, 0);
        fold(acc3); acc3 = __builtin_amdgcn_mfma_f32_32x32x8f16(rd(), Bf, Z, 0, 0, 0);
    }
    fold(acc0); fold(acc1); fold(acc2); fold(acc3);

    // epilogue: merge lane-halves, add |q~|^2, sqrt, sum 32 queries
    m = fminf(m, __shfl_xor(m, 32, 64));
    float d = sqrtf(fmaxf(m + nq, 0.f));
    d += __shfl_xor(d, 16, 64);
    d += __shfl_xor(d,  8, 64);
    d += __shfl_xor(d,  4, 64);
    d += __shfl_xor(d,  2, 64);
    d += __shfl_xor(d,  1, 64);
    if (lane == 0) wred[wave] = d;
    __syncthreads();
    if (tid == 0) {
        float s = ((wred[0] + wred[1]) + (wred[2] + wred[3]))
                + ((wred[4] + wred[5]) + (wred[6] + wred[7]));
        Bsum[bx] = s;
    }
}

__global__ __launch_bounds__(256) void cd_final(
        const float* __restrict__ Bsum, float* __restrict__ out) {
    const int tid = threadIdx.x;
    float s = Bsum[tid];             // 256 values, one per thread
    __shared__ float red[256];
    red[tid] = s;
    __syncthreads();
    for (int off = 128; off > 0; off >>= 1) {
        if (tid < off) red[tid] += red[tid + off];
        __syncthreads();
    }
    if (tid == 0) out[0] = red[0] * (1.0f / (float)(BATCH * NPTS));
}

extern "C" void kernel_launch(void* const* d_in, const int* in_sizes, int n_in,
                              void* d_out, int out_size, void* d_ws, size_t ws_size,
                              hipStream_t stream) {
    const float* pred = (const float*)d_in[0];
    const float* targ = (const float*)d_in[1];
    float* Bsum = (float*)d_ws;     // 1 KB
    float* out  = (float*)d_out;

    cd_mfma<<<K1_BLOCKS, THREADS, 0, stream>>>(pred, targ, Bsum);
    cd_final<<<1, 256, 0, stream>>>(Bsum, out);
}